// Round 1
// baseline (1616.065 us; speedup 1.0000x reference)
//
#include <hip/hip_runtime.h>
#include <stdint.h>

#define GD   34
#define GP   36          // padded grid (zero halo; safe for conv AND for >0.1 maxpool tests)
#define NPIX 1156        // 34*34
#define NT   256
#define PPT  5           // pixels per thread: p = tid + i*256  (i<4 always active; i==4 active iff tid<132)
#define NB   1024

// wave0 scans a 1024-bin LDS histogram, finds the bin containing rank KK,
// writes sel_bin/sel_rem, and zeroes the histogram behind itself.
#define SCAN_PASS(KK) do {                                                         \
    if (wid == 0) {                                                                \
      const int base2 = lane << 4;                                                 \
      int c16[16]; int csum = 0;                                                   \
      _Pragma("unroll")                                                            \
      for (int j = 0; j < 16; ++j) { c16[j] = hist[base2+j]; hist[base2+j] = 0; csum += c16[j]; } \
      int inc = csum;                                                              \
      _Pragma("unroll")                                                            \
      for (int off2 = 1; off2 < 64; off2 <<= 1) { int vv = __shfl_up(inc, off2); if (lane >= off2) inc += vv; } \
      const int excl = inc - csum;                                                 \
      if ((KK) >= excl && (KK) < inc) {                                            \
        int rem = (KK) - excl; int cum = 0;                                        \
        _Pragma("unroll")                                                          \
        for (int j = 0; j < 16; ++j) {                                             \
          if (rem >= cum && rem < cum + c16[j]) { sel_bin = base2 + j; sel_rem = rem - cum; } \
          cum += c16[j];                                                           \
        }                                                                          \
      }                                                                            \
    }                                                                              \
  } while (0)

__global__ __launch_bounds__(NT, 3)
void ca_kernel(const float* __restrict__ cell_in,   // [B,4,34,34]
               const float* __restrict__ food_in,   // [B,34,34]
               const float* __restrict__ fc1_w,     // [64,12]
               const float* __restrict__ fc1_b,     // [64]
               const float* __restrict__ fc2_w,     // [4,64]
               const float* __restrict__ fc2_b,     // [4]
               const float* __restrict__ sk_g,      // [19,19]
               const int*   __restrict__ steps_p,   // scalar
               float* __restrict__ out)             // [cell | food | tpv | lc]
{
  __shared__ float cbuf[4][GP*GP];                 // padded cell state, halo stays 0
  __shared__ float scratch[2704];                  // init: 52x52 food tile; steps: x0buf[1296] + hist[1024]
  __shared__ __align__(16) float w1[64*12];
  __shared__ float b1s[64];
  __shared__ __align__(16) float w2t[64*4];        // fc2_w transposed to [o][c] for float4 reads
  __shared__ float b2s[4];
  __shared__ float sk[361];
  __shared__ int   icl[4], inz[4];
  __shared__ int   sel_bin, sel_rem;
  __shared__ float fsum[4];
  __shared__ int   lcnt[4];

  float* x0buf = scratch;                          // 1296 floats (36x36, halo 0)
  int*   hist  = (int*)(scratch + 1296);           // 1024 ints

  const int tid  = threadIdx.x;
  const int b    = blockIdx.x;
  const int lane = tid & 63;
  const int wid  = tid >> 6;
  const int nsteps = steps_p[0];

  int pbase[PPT];
#pragma unroll
  for (int i = 0; i < PPT; ++i) {
    int p = tid + i*NT;
    int r = (p < NPIX) ? (p / GD) : 0;
    int c = (p < NPIX) ? (p % GD) : 0;
    pbase[i] = (r+1)*GP + (c+1);
  }

  // ---------------- init: zero LDS, load weights ----------------
  for (int idx = tid; idx < 4*GP*GP; idx += NT) (&cbuf[0][0])[idx] = 0.f;
  for (int idx = tid; idx < 2704; idx += NT) scratch[idx] = 0.f;
  for (int idx = tid; idx < 768;  idx += NT) w1[idx] = fc1_w[idx];
  if (tid < 64) b1s[tid] = fc1_b[tid];
  { int o = tid >> 2, cc = tid & 3; w2t[o*4+cc] = fc2_w[cc*64+o]; }
  if (tid < 4) b2s[tid] = fc2_b[tid];
  for (int idx = tid; idx < 361; idx += NT) sk[idx] = sk_g[idx];
  __syncthreads();

  // load cell + stage food (52x52, 9-halo for 19x19 conv with pad 9)
  float x[PPT][4];
#pragma unroll
  for (int i = 0; i < PPT; ++i) {
    int p = tid + i*NT;
    if (p < NPIX) {
      int r = p / GD, c = p % GD;
      const float* gi = cell_in + (size_t)b*4*NPIX + p;
      float v0 = gi[0], v1 = gi[NPIX], v2 = gi[2*NPIX], v3 = gi[3*NPIX];
      cbuf[0][pbase[i]] = v0; cbuf[1][pbase[i]] = v1;
      cbuf[2][pbase[i]] = v2; cbuf[3][pbase[i]] = v3;
      x[i][0]=v0; x[i][1]=v1; x[i][2]=v2; x[i][3]=v3;
      scratch[(r+9)*52 + (c+9)] = food_in[(size_t)b*NPIX + p];
    } else { x[i][0]=0.f; x[i][1]=0.f; x[i][2]=0.f; x[i][3]=0.f; }
  }
  __syncthreads();

  // ---------------- scent: 19x19 gaussian conv, once ----------------
  float scent[PPT];
#pragma unroll
  for (int i = 0; i < PPT; ++i) {
    float s = 0.f;
    int p = tid + i*NT;
    if (p < NPIX) {
      int r = p / GD, c = p % GD;
      for (int dr = 0; dr < 19; ++dr) {
        const float* frow = scratch + (r+dr)*52 + c;
        const float* krow = sk + dr*19;
#pragma unroll
        for (int dc = 0; dc < 19; ++dc) s = fmaf(frow[dc], krow[dc], s);
      }
    }
    scent[i] = s;
  }
  __syncthreads();
  for (int idx = tid; idx < 2704; idx += NT) scratch[idx] = 0.f;  // x0buf halo must be 0
  __syncthreads();

  const float4* w1v = (const float4*)w1;
  const float4* w2v = (const float4*)w2t;

  // ---------------- 32 steps ----------------
  for (int s = 0; s < nsteps; ++s) {
    // --- A: clear hist, inject scent into ch3, count cl = #(ch0 > 0.8) ---
    hist[tid] = 0; hist[tid+256] = 0; hist[tid+512] = 0; hist[tid+768] = 0;
    int cnt = 0;
#pragma unroll
    for (int i = 0; i < PPT; ++i) {
      if (tid + i*NT < NPIX) {
        cbuf[3][pbase[i]] = scent[i];
        cnt += (x[i][0] > 0.8f) ? 1 : 0;   // x == current cbuf ch0 at own pixels
      }
    }
#pragma unroll
    for (int off = 32; off; off >>= 1) cnt += __shfl_down(cnt, off);
    if (lane == 0) icl[wid] = cnt;
    __syncthreads();                                   // sync1
    const int cl = icl[0]+icl[1]+icl[2]+icl[3];

    // --- B: pre_mask, perception y[12], MLP, x = cell + upd, stage x0 ---
    float y[PPT][12];
    unsigned premask = 0;
#pragma unroll
    for (int i = 0; i < PPT; ++i) {
      if (tid + i*NT < NPIX) {
        const int bb = pbase[i];
        float mx0 = 0.f;
#pragma unroll
        for (int ch = 0; ch < 4; ++ch) {
          const float* cb = cbuf[ch];
          float t00=cb[bb-GP-1], t01=cb[bb-GP], t02=cb[bb-GP+1];
          float t10=cb[bb-1],    t11=cb[bb],    t12=cb[bb+1];
          float t20=cb[bb+GP-1], t21=cb[bb+GP], t22=cb[bb+GP+1];
          if (ch == 0) {
            mx0 = fmaxf(fmaxf(fmaxf(t00,t01),fmaxf(t02,t10)),
                  fmaxf(fmaxf(t11,t12),fmaxf(fmaxf(t20,t21),t22)));
          }
          y[i][ch]   = t11;
          y[i][4+ch] = ((t02 - t00) + 2.f*(t12 - t10) + (t22 - t20)) * 0.125f;  // sobel-x
          y[i][8+ch] = ((t20 - t00) + 2.f*(t21 - t01) + (t22 - t02)) * 0.125f;  // sobel-y
        }
        if (mx0 > 0.1f) premask |= (1u << i);
      } else {
#pragma unroll
        for (int j = 0; j < 12; ++j) y[i][j] = 0.f;
      }
    }

    float us[PPT][4];
#pragma unroll
    for (int i = 0; i < PPT; ++i) { us[i][0]=b2s[0]; us[i][1]=b2s[1]; us[i][2]=b2s[2]; us[i][3]=b2s[3]; }
#pragma unroll 2
    for (int o = 0; o < 64; ++o) {
      const float4 wa = w1v[o*3+0];
      const float4 wb = w1v[o*3+1];
      const float4 wc = w1v[o*3+2];
      const float  bo = b1s[o];
      const float4 wo = w2v[o];
#pragma unroll
      for (int i = 0; i < PPT; ++i) {
        float t = bo;
        t = fmaf(y[i][0], wa.x, t); t = fmaf(y[i][1], wa.y, t);
        t = fmaf(y[i][2], wa.z, t); t = fmaf(y[i][3], wa.w, t);
        t = fmaf(y[i][4], wb.x, t); t = fmaf(y[i][5], wb.y, t);
        t = fmaf(y[i][6], wb.z, t); t = fmaf(y[i][7], wb.w, t);
        t = fmaf(y[i][8], wc.x, t); t = fmaf(y[i][9], wc.y, t);
        t = fmaf(y[i][10],wc.z, t); t = fmaf(y[i][11],wc.w, t);
        t = fmaxf(t, 0.f);
        us[i][0] = fmaf(t, wo.x, us[i][0]);
        us[i][1] = fmaf(t, wo.y, us[i][1]);
        us[i][2] = fmaf(t, wo.z, us[i][2]);
        us[i][3] = fmaf(t, wo.w, us[i][3]);
      }
    }
#pragma unroll
    for (int i = 0; i < PPT; ++i) {
      x[i][0] = y[i][0] + us[i][0];
      x[i][1] = y[i][1] + us[i][1];
      x[i][2] = y[i][2] + us[i][2];
      x[i][3] = y[i][3] + us[i][3];
      if (tid + i*NT < NPIX) x0buf[pbase[i]] = x[i][0];   // PRE-mask, PRE-clip (reference order)
    }
    __syncthreads();                                   // sync2

    // --- C: post_mask, apply masks+clips, count zeros, radix hist pass 1 ---
    unsigned uu[PPT];
    int nzc = 0;
#pragma unroll
    for (int i = 0; i < PPT; ++i) {
      uu[i] = 0u;
      if (tid + i*NT < NPIX) {
        const int bb = pbase[i];
        float m0 = fmaxf(fmaxf(fmaxf(x0buf[bb-GP-1],x0buf[bb-GP]),fmaxf(x0buf[bb-GP+1],x0buf[bb-1])),
                   fmaxf(fmaxf(x0buf[bb],x0buf[bb+1]),fmaxf(fmaxf(x0buf[bb+GP-1],x0buf[bb+GP]),x0buf[bb+GP+1])));
        float v0, v1, v2, v3;
        if ((m0 > 0.1f) && ((premask >> i) & 1u)) {
          v0 = fminf(fmaxf(x[i][0],   0.f),  1.f);     // clip(-10,10) then clip(0,1) == clip(0,1)
          v1 = fminf(fmaxf(x[i][1], -10.f), 10.f);
          v2 = fminf(fmaxf(x[i][2], -10.f), 10.f);
          v3 = fminf(fmaxf(x[i][3], -10.f), 10.f);
        } else { v0 = 0.f; v1 = 0.f; v2 = 0.f; v3 = 0.f; }
        x[i][0]=v0; x[i][1]=v1; x[i][2]=v2; x[i][3]=v3;
        unsigned u = __float_as_uint(v0);              // v0 in [0,1], +0 only -> uint order == float order
        uu[i] = u;
        if (u == 0u) ++nzc;
        else atomicAdd(&hist[u >> 20], 1);
      }
    }
#pragma unroll
    for (int off = 32; off; off >>= 1) nzc += __shfl_down(nzc, off);
    if (lane == 0) inz[wid] = nzc;
    __syncthreads();                                   // sync3
    const int nz = inz[0]+inz[1]+inz[2]+inz[3];

    // --- D: k-th order statistic (k = min(cl,1155), take_along_axis clamps) ---
    int k = (cl < NPIX) ? cl : (NPIX-1);
    float kth = 0.f;
    if (k >= nz) {                                     // else: kth element is a zero -> kth = 0
      const int k2 = k - nz;                           // rank among positives; k2 < npos guaranteed
      SCAN_PASS(k2);
      __syncthreads();                                 // sync4
      const int bin1 = sel_bin; const int kr2 = sel_rem;
#pragma unroll
      for (int i = 0; i < PPT; ++i)
        if ((tid + i*NT < NPIX) && uu[i] != 0u && (uu[i] >> 20) == (unsigned)bin1)
          atomicAdd(&hist[(uu[i] >> 10) & 1023u], 1);
      __syncthreads();                                 // sync5
      SCAN_PASS(kr2);
      __syncthreads();                                 // sync6
      const int bin2 = sel_bin; const int kr3 = sel_rem;
      const unsigned pref2 = (((unsigned)bin1) << 10) | (unsigned)bin2;
#pragma unroll
      for (int i = 0; i < PPT; ++i)
        if ((tid + i*NT < NPIX) && uu[i] != 0u && (uu[i] >> 10) == pref2)
          atomicAdd(&hist[uu[i] & 1023u], 1);
      __syncthreads();                                 // sync7
      SCAN_PASS(kr3);
      __syncthreads();                                 // sync8
      kth = __uint_as_float((((unsigned)bin1) << 20) | (((unsigned)bin2) << 10) | (unsigned)sel_bin);
    }

    // --- write back: keep strictly greater than kth (exact-bit ties dropped) ---
#pragma unroll
    for (int i = 0; i < PPT; ++i) {
      if (tid + i*NT < NPIX) {
        float v0 = x[i][0];
        v0 = (v0 > kth) ? v0 : 0.f;
        x[i][0] = v0;
        cbuf[0][pbase[i]] = v0;
        cbuf[1][pbase[i]] = x[i][1];
        cbuf[2][pbase[i]] = x[i][2];
        cbuf[3][pbase[i]] = x[i][3];
      }
    }
    // no sync needed here: next-step phase A touches only own pixels / hist slots
    // whose last foreign use is separated by sync3 (shortcut) or sync8 (select).
  }

  // ---------------- epilogue: outputs ----------------
  const size_t CELL_N = (size_t)4*NPIX*NB;
  const size_t FOOD_N = (size_t)NPIX*NB;
  float tp = 0.f; int lcv = 0;
#pragma unroll
  for (int i = 0; i < PPT; ++i) {
    int p = tid + i*NT;
    if (p < NPIX) {
      size_t go = (size_t)b*4*NPIX + p;
      out[go]            = x[i][0];
      out[go +   NPIX]   = x[i][1];
      out[go + 2*NPIX]   = x[i][2];
      out[go + 3*NPIX]   = x[i][3];
      out[CELL_N + (size_t)b*NPIX + p] = food_in[(size_t)b*NPIX + p];  // pass-through
      tp += x[i][0];
      lcv += (x[i][0] > 0.1f) ? 1 : 0;
    }
  }
#pragma unroll
  for (int off = 32; off; off >>= 1) { tp += __shfl_down(tp, off); lcv += __shfl_down(lcv, off); }
  if (lane == 0) { fsum[wid] = tp; lcnt[wid] = lcv; }
  __syncthreads();
  if (tid == 0) {
    out[CELL_N + FOOD_N + b]      = fsum[0]+fsum[1]+fsum[2]+fsum[3];
    out[CELL_N + FOOD_N + NB + b] = (float)(lcnt[0]+lcnt[1]+lcnt[2]+lcnt[3]);
  }
}

extern "C" void kernel_launch(void* const* d_in, const int* in_sizes, int n_in,
                              void* d_out, int out_size, void* d_ws, size_t ws_size,
                              hipStream_t stream) {
  const float* cell  = (const float*)d_in[0];
  const float* food  = (const float*)d_in[1];
  const float* fc1w  = (const float*)d_in[2];
  const float* fc1b  = (const float*)d_in[3];
  const float* fc2w  = (const float*)d_in[4];
  const float* fc2b  = (const float*)d_in[5];
  const float* sk    = (const float*)d_in[6];
  const int*   steps = (const int*)d_in[7];
  float* out = (float*)d_out;
  ca_kernel<<<NB, NT, 0, stream>>>(cell, food, fc1w, fc1b, fc2w, fc2b, sk, steps, out);
}

// Round 2
// 390.553 us; speedup vs baseline: 4.1379x; 4.1379x over previous
//
#include <hip/hip_runtime.h>
#include <stdint.h>

#define GD   34
#define GP   36          // padded grid (zero halo)
#define NPIX 1156
#define NT   256
#define PPT  5           // p = tid + i*256
#define NB   1024

// wave0 scans the 1024-bin LDS histogram, finds the bin containing rank KK,
// writes sel_bin/sel_rem, zeroes the histogram behind itself.
#define SCAN_PASS(KK) do {                                                         \
    if (wid == 0) {                                                                \
      const int base2 = lane << 4;                                                 \
      int c16[16]; int csum = 0;                                                   \
      _Pragma("unroll")                                                            \
      for (int j = 0; j < 16; ++j) { c16[j] = hist[base2+j]; hist[base2+j] = 0; csum += c16[j]; } \
      int inc = csum;                                                              \
      _Pragma("unroll")                                                            \
      for (int off2 = 1; off2 < 64; off2 <<= 1) { int vv = __shfl_up(inc, off2); if (lane >= off2) inc += vv; } \
      const int excl = inc - csum;                                                 \
      if ((KK) >= excl && (KK) < inc) {                                            \
        int rem = (KK) - excl; int cum = 0;                                        \
        _Pragma("unroll")                                                          \
        for (int j = 0; j < 16; ++j) {                                             \
          if (rem >= cum && rem < cum + c16[j]) { sel_bin = base2 + j; sel_rem = rem - cum; } \
          cum += c16[j];                                                           \
        }                                                                          \
      }                                                                            \
    }                                                                              \
  } while (0)

__global__ __launch_bounds__(NT, 4)   // cap 128 VGPR: 4 waves/SIMD, 4 blocks/CU
void ca_kernel(const float* __restrict__ cell_in,   // [B,4,34,34]
               const float* __restrict__ food_in,   // [B,34,34]
               const float* __restrict__ fc1_w,     // [64,12] (wave-uniform scalar reads)
               const float* __restrict__ fc1_b,     // [64]
               const float* __restrict__ fc2_w,     // [4,64]
               const float* __restrict__ fc2_b,     // [4]
               const float* __restrict__ sk_g,      // [19,19]
               const int*   __restrict__ steps_p,
               float* __restrict__ out)             // [cell | food | tpv | lc]
{
  __shared__ float cbuf[3][GP*GP];   // ch0..2 only; ch3 == scent (step-invariant), never stored
  __shared__ float scratch[2704];    // init: 52x52 food; steps: x0buf[1296] + hist[1024] + premb bytes
  __shared__ int   icl[2][4];        // double-buffered living count (race-free across steps)
  __shared__ int   inzaz[4];         // packed: nz | az<<16
  __shared__ int   sel_bin, sel_rem;
  __shared__ float fsum[4];
  __shared__ int   lcnt[4];

  float* x0buf = scratch;
  int*   hist  = (int*)(scratch + 1296);
  unsigned char* premb = (unsigned char*)(scratch + 2320);  // 1296 bytes, halo stays 0

  const int tid  = threadIdx.x;
  const int b    = blockIdx.x;
  const int lane = tid & 63;
  const int wid  = tid >> 6;
  const int nsteps = steps_p[0];

  int pbase[PPT];
#pragma unroll
  for (int i = 0; i < PPT; ++i) {
    int p = tid + i*NT;
    int r = (p < NPIX) ? (p / GD) : 0;
    int c = (p < NPIX) ? (p % GD) : 0;
    pbase[i] = (r+1)*GP + (c+1);
  }

  // ---------------- init ----------------
  for (int idx = tid; idx < 3*GP*GP; idx += NT) (&cbuf[0][0])[idx] = 0.f;
  for (int idx = tid; idx < 2704;    idx += NT) scratch[idx] = 0.f;   // also zeroes hist+premb once
  __syncthreads();

  float v3k[PPT];
  int cnt0 = 0;
#pragma unroll
  for (int i = 0; i < PPT; ++i) {
    v3k[i] = 0.f;
    int p = tid + i*NT;
    if (p < NPIX) {
      int r = p / GD, c = p % GD;
      const float* gi = cell_in + (size_t)b*4*NPIX + p;
      float v0 = gi[0], v1 = gi[NPIX], v2 = gi[2*NPIX], v3 = gi[3*NPIX];
      cbuf[0][pbase[i]] = v0; cbuf[1][pbase[i]] = v1; cbuf[2][pbase[i]] = v2;
      v3k[i] = v3;
      cnt0 += (v0 > 0.8f) ? 1 : 0;
      scratch[(r+9)*52 + (c+9)] = food_in[(size_t)b*NPIX + p];  // 9-halo for 19x19 conv
    }
  }
#pragma unroll
  for (int off = 32; off; off >>= 1) cnt0 += __shfl_down(cnt0, off);
  if (lane == 0) icl[0][wid] = cnt0;
  __syncthreads();

  // scent: 19x19 gaussian conv (once); kernel weights via uniform scalar loads
  float scent[PPT];
#pragma unroll
  for (int i = 0; i < PPT; ++i) {
    float ssum = 0.f;
    int p = tid + i*NT;
    if (p < NPIX) {
      int r = p / GD, c = p % GD;
      for (int dr = 0; dr < 19; ++dr) {
        const float* frow = scratch + (r+dr)*52 + c;
        const float* krow = sk_g + dr*19;
#pragma unroll
        for (int dc = 0; dc < 19; ++dc) ssum = fmaf(frow[dc], krow[dc], ssum);
      }
    }
    scent[i] = ssum;
  }
  __syncthreads();
  for (int idx = tid; idx < 2704; idx += NT) scratch[idx] = 0.f;
  __syncthreads();
#pragma unroll
  for (int i = 0; i < PPT; ++i) if (tid + i*NT < NPIX) x0buf[pbase[i]] = scent[i];
  __syncthreads();
  // ch3 sobels are step-invariant (ch3 := scent every step): precompute once
  float sxs[PPT], sys[PPT];
#pragma unroll
  for (int i = 0; i < PPT; ++i) {
    const int bb = pbase[i];
    float t00=x0buf[bb-GP-1], t01=x0buf[bb-GP], t02=x0buf[bb-GP+1];
    float t10=x0buf[bb-1],                      t12=x0buf[bb+1];
    float t20=x0buf[bb+GP-1], t21=x0buf[bb+GP], t22=x0buf[bb+GP+1];
    sxs[i] = ((t02 - t00) + 2.f*(t12 - t10) + (t22 - t20)) * 0.125f;
    sys[i] = ((t20 - t00) + 2.f*(t21 - t01) + (t22 - t02)) * 0.125f;
  }

  const float b2r0 = fc2_b[0], b2r1 = fc2_b[1], b2r2 = fc2_b[2], b2r3 = fc2_b[3];

  // ---------------- steps ----------------
  for (int s = 0; s < nsteps; ++s) {
    __syncthreads();                       // syncW: prev writeback -> B1 reads
    // --- B1: premask = maxpool3(ch0) > 0.1; stage as bytes for dilation ---
    unsigned pm = 0;
#pragma unroll
    for (int i = 0; i < PPT; ++i) {
      const int bb = pbase[i];
      const float* cb = cbuf[0];
      float m = fmaxf(fmaxf(fmaxf(cb[bb-GP-1],cb[bb-GP]),fmaxf(cb[bb-GP+1],cb[bb-1])),
                fmaxf(fmaxf(cb[bb],cb[bb+1]),fmaxf(fmaxf(cb[bb+GP-1],cb[bb+GP]),cb[bb+GP+1])));
      bool t = (m > 0.1f);
      if (tid + i*NT < NPIX) premb[bb] = t ? 1 : 0;
      if (t) pm |= (1u << i);
    }
    __syncthreads();                       // syncB
    // --- B2: dilated activity; MLP only if this wave has any active pixel ---
    int act = 0;
#pragma unroll
    for (int i = 0; i < PPT; ++i) {
      const int bb = pbase[i];
      int a = premb[bb-GP-1]|premb[bb-GP]|premb[bb-GP+1]|premb[bb-1]|premb[bb]|premb[bb+1]
             |premb[bb+GP-1]|premb[bb+GP]|premb[bb+GP+1];
      if (tid + i*NT < NPIX) act |= a;
    }
    float xs0[PPT], xs1[PPT], xs2[PPT], xs3[PPT];
    if (__any(act)) {
      float y[PPT][12];
#pragma unroll
      for (int i = 0; i < PPT; ++i) {
        const int bb = pbase[i];
#pragma unroll
        for (int ch = 0; ch < 3; ++ch) {
          const float* cb = cbuf[ch];
          float t00=cb[bb-GP-1], t01=cb[bb-GP], t02=cb[bb-GP+1];
          float t10=cb[bb-1],    t11=cb[bb],    t12=cb[bb+1];
          float t20=cb[bb+GP-1], t21=cb[bb+GP], t22=cb[bb+GP+1];
          y[i][ch]   = t11;
          y[i][4+ch] = ((t02 - t00) + 2.f*(t12 - t10) + (t22 - t20)) * 0.125f;
          y[i][8+ch] = ((t20 - t00) + 2.f*(t21 - t01) + (t22 - t02)) * 0.125f;
        }
        y[i][3] = scent[i]; y[i][7] = sxs[i]; y[i][11] = sys[i];
      }
      float us0[PPT], us1[PPT], us2[PPT], us3[PPT];
#pragma unroll
      for (int i = 0; i < PPT; ++i) { us0[i]=b2r0; us1[i]=b2r1; us2[i]=b2r2; us3[i]=b2r3; }
      for (int o = 0; o < 64; ++o) {       // weights: wave-uniform scalar loads (K$, no DS/VGPR cost)
        const float* wr = fc1_w + o*12;
        const float wA=wr[0], wB=wr[1], wC=wr[2], wD=wr[3], wE=wr[4], wF=wr[5],
                    wG=wr[6], wH=wr[7], wI=wr[8], wJ=wr[9], wK=wr[10], wL=wr[11];
        const float bo = fc1_b[o];
        const float q0 = fc2_w[o], q1 = fc2_w[64+o], q2 = fc2_w[128+o], q3 = fc2_w[192+o];
#pragma unroll
        for (int i = 0; i < PPT; ++i) {
          float t = bo;
          t = fmaf(y[i][0], wA, t); t = fmaf(y[i][1], wB, t);
          t = fmaf(y[i][2], wC, t); t = fmaf(y[i][3], wD, t);
          t = fmaf(y[i][4], wE, t); t = fmaf(y[i][5], wF, t);
          t = fmaf(y[i][6], wG, t); t = fmaf(y[i][7], wH, t);
          t = fmaf(y[i][8], wI, t); t = fmaf(y[i][9], wJ, t);
          t = fmaf(y[i][10], wK, t); t = fmaf(y[i][11], wL, t);
          t = fmaxf(t, 0.f);
          us0[i] = fmaf(t, q0, us0[i]); us1[i] = fmaf(t, q1, us1[i]);
          us2[i] = fmaf(t, q2, us2[i]); us3[i] = fmaf(t, q3, us3[i]);
        }
      }
#pragma unroll
      for (int i = 0; i < PPT; ++i) {
        xs0[i] = y[i][0] + us0[i]; xs1[i] = y[i][1] + us1[i];
        xs2[i] = y[i][2] + us2[i]; xs3[i] = y[i][3] + us3[i];
        if (tid + i*NT < NPIX) x0buf[pbase[i]] = xs0[i];
      }
    } else {
      // inactive wave: x0buf left stale — only ever consumed by premask-false pixels
#pragma unroll
      for (int i = 0; i < PPT; ++i) { xs0[i]=0.f; xs1[i]=0.f; xs2[i]=0.f; xs3[i]=0.f; }
    }
    __syncthreads();                       // sync2
    // --- C: post_mask, masks+clips, counts (no atomics) ---
    int packed = 0;                        // nz | az<<16
    float v0s[PPT];
#pragma unroll
    for (int i = 0; i < PPT; ++i) {
      v0s[i] = 0.f;
      if (tid + i*NT < NPIX) {
        const int bb = pbase[i];
        float m0 = fmaxf(fmaxf(fmaxf(x0buf[bb-GP-1],x0buf[bb-GP]),fmaxf(x0buf[bb-GP+1],x0buf[bb-1])),
                   fmaxf(fmaxf(x0buf[bb],x0buf[bb+1]),fmaxf(fmaxf(x0buf[bb+GP-1],x0buf[bb+GP]),x0buf[bb+GP+1])));
        bool alive = (m0 > 0.1f) && ((pm >> i) & 1u);
        float v0 = alive ? fminf(fmaxf(xs0[i],   0.f),  1.f) : 0.f;
        float v1 = alive ? fminf(fmaxf(xs1[i], -10.f), 10.f) : 0.f;
        float v2 = alive ? fminf(fmaxf(xs2[i], -10.f), 10.f) : 0.f;
        float v3 = alive ? fminf(fmaxf(xs3[i], -10.f), 10.f) : 0.f;
        cbuf[1][bb] = v1; cbuf[2][bb] = v2; v3k[i] = v3;
        v0s[i] = v0;
        int zer = (v0 == 0.f) ? 1 : 0;
        int azf = (zer && v1 == 0.f && v2 == 0.f && v3 == 0.f) ? 1 : 0;
        packed += zer + (azf << 16);
      }
    }
#pragma unroll
    for (int off = 32; off; off >>= 1) packed += __shfl_down(packed, off);
    if (lane == 0) inzaz[wid] = packed;
    __syncthreads();                       // sync3
    const int t01 = inzaz[0]+inzaz[1]+inzaz[2]+inzaz[3];
    const int nz = t01 & 0xffff, az = t01 >> 16;
    const int cl = icl[s&1][0]+icl[s&1][1]+icl[s&1][2]+icl[s&1][3];
    const int k  = (cl < NPIX) ? cl : (NPIX-1);
    float kth = 0.f;
    if (k >= nz) {                         // rare after first steps: k-th value nonzero -> radix select
      const int k2 = k - nz;
#pragma unroll
      for (int i = 0; i < PPT; ++i) {
        unsigned u = __float_as_uint(v0s[i]);
        if ((tid + i*NT < NPIX) && u != 0u) atomicAdd(&hist[u >> 20], 1);
      }
      __syncthreads();
      SCAN_PASS(k2);
      __syncthreads();
      const int bin1 = sel_bin; const int kr2 = sel_rem;
#pragma unroll
      for (int i = 0; i < PPT; ++i) {
        unsigned u = __float_as_uint(v0s[i]);
        if ((tid + i*NT < NPIX) && u != 0u && (u >> 20) == (unsigned)bin1)
          atomicAdd(&hist[(u >> 10) & 1023u], 1);
      }
      __syncthreads();
      SCAN_PASS(kr2);
      __syncthreads();
      const int bin2 = sel_bin; const int kr3 = sel_rem;
      const unsigned pref2 = (((unsigned)bin1) << 10) | (unsigned)bin2;
#pragma unroll
      for (int i = 0; i < PPT; ++i) {
        unsigned u = __float_as_uint(v0s[i]);
        if ((tid + i*NT < NPIX) && u != 0u && (u >> 10) == pref2)
          atomicAdd(&hist[u & 1023u], 1);
      }
      __syncthreads();
      SCAN_PASS(kr3);
      __syncthreads();
      kth = __uint_as_float((((unsigned)bin1) << 20) | (((unsigned)bin2) << 10) | (unsigned)sel_bin);
    }
    // --- writeback + next step's living count ---
    int cnt = 0;
#pragma unroll
    for (int i = 0; i < PPT; ++i) {
      if (tid + i*NT < NPIX) {
        float w0 = (v0s[i] > kth) ? v0s[i] : 0.f;
        cbuf[0][pbase[i]] = w0;
        cnt += (w0 > 0.8f) ? 1 : 0;
      }
    }
#pragma unroll
    for (int off = 32; off; off >>= 1) cnt += __shfl_down(cnt, off);
    if (lane == 0) icl[(s+1)&1][wid] = cnt;
    if (az == NPIX) break;                 // all-zero state is an exact fixed point of the update
  }

  // ---------------- epilogue ----------------
  const size_t CELL_N = (size_t)4*NPIX*NB;
  const size_t FOOD_N = (size_t)NPIX*NB;
  float tp = 0.f; int lcv = 0;
#pragma unroll
  for (int i = 0; i < PPT; ++i) {
    int p = tid + i*NT;
    if (p < NPIX) {
      const int bb = pbase[i];
      float c0 = cbuf[0][bb], c1 = cbuf[1][bb], c2 = cbuf[2][bb];   // self-written: no sync needed
      size_t go = (size_t)b*4*NPIX + p;
      out[go]          = c0;
      out[go +   NPIX] = c1;
      out[go + 2*NPIX] = c2;
      out[go + 3*NPIX] = v3k[i];
      out[CELL_N + (size_t)b*NPIX + p] = food_in[(size_t)b*NPIX + p];
      tp += c0;
      lcv += (c0 > 0.1f) ? 1 : 0;
    }
  }
#pragma unroll
  for (int off = 32; off; off >>= 1) { tp += __shfl_down(tp, off); lcv += __shfl_down(lcv, off); }
  if (lane == 0) { fsum[wid] = tp; lcnt[wid] = lcv; }
  __syncthreads();
  if (tid == 0) {
    out[CELL_N + FOOD_N + b]      = fsum[0]+fsum[1]+fsum[2]+fsum[3];
    out[CELL_N + FOOD_N + NB + b] = (float)(lcnt[0]+lcnt[1]+lcnt[2]+lcnt[3]);
  }
}

extern "C" void kernel_launch(void* const* d_in, const int* in_sizes, int n_in,
                              void* d_out, int out_size, void* d_ws, size_t ws_size,
                              hipStream_t stream) {
  const float* cell  = (const float*)d_in[0];
  const float* food  = (const float*)d_in[1];
  const float* fc1w  = (const float*)d_in[2];
  const float* fc1b  = (const float*)d_in[3];
  const float* fc2w  = (const float*)d_in[4];
  const float* fc2b  = (const float*)d_in[5];
  const float* sk    = (const float*)d_in[6];
  const int*   steps = (const int*)d_in[7];
  float* out = (float*)d_out;
  ca_kernel<<<NB, NT, 0, stream>>>(cell, food, fc1w, fc1b, fc2w, fc2b, sk, steps, out);
}

// Round 3
// 380.370 us; speedup vs baseline: 4.2487x; 1.0268x over previous
//
#include <hip/hip_runtime.h>
#include <stdint.h>

#define GD   34
#define GP   36          // padded grid (zero halo)
#define NPIX 1156
#define NT   256
#define PPT  5           // p = tid + i*256
#define NB   1024

// wave0 scans the 1024-bin LDS histogram, finds the bin containing rank KK,
// writes sel_bin/sel_rem, zeroes the histogram behind itself.
#define SCAN_PASS(KK) do {                                                         \
    if (wid == 0) {                                                                \
      const int base2 = lane << 4;                                                 \
      int c16[16]; int csum = 0;                                                   \
      _Pragma("unroll")                                                            \
      for (int j = 0; j < 16; ++j) { c16[j] = hist[base2+j]; hist[base2+j] = 0; csum += c16[j]; } \
      int inc = csum;                                                              \
      _Pragma("unroll")                                                            \
      for (int off2 = 1; off2 < 64; off2 <<= 1) { int vv = __shfl_up(inc, off2); if (lane >= off2) inc += vv; } \
      const int excl = inc - csum;                                                 \
      if ((KK) >= excl && (KK) < inc) {                                            \
        int rem = (KK) - excl; int cum = 0;                                        \
        _Pragma("unroll")                                                          \
        for (int j = 0; j < 16; ++j) {                                             \
          if (rem >= cum && rem < cum + c16[j]) { sel_bin = base2 + j; sel_rem = rem - cum; } \
          cum += c16[j];                                                           \
        }                                                                          \
      }                                                                            \
    }                                                                              \
  } while (0)

// MLP over a chunk of CW pixels: keeps y live for only CW pixels at a time
// (register-pressure cap — the R2 compiler spilled y[5][12] to scratch).
#define MLP_CHUNK(C0, CW) do {                                                     \
    float y[CW][12];                                                               \
    _Pragma("unroll")                                                              \
    for (int i = 0; i < CW; ++i) {                                                 \
      const int bb = pbase[C0+i];                                                  \
      _Pragma("unroll")                                                            \
      for (int ch = 0; ch < 3; ++ch) {                                             \
        const float* cb = cbuf[ch];                                                \
        float t00=cb[bb-GP-1], t01=cb[bb-GP], t02=cb[bb-GP+1];                     \
        float t10=cb[bb-1],    t11=cb[bb],    t12=cb[bb+1];                        \
        float t20=cb[bb+GP-1], t21=cb[bb+GP], t22=cb[bb+GP+1];                     \
        y[i][ch]   = t11;                                                          \
        y[i][4+ch] = ((t02 - t00) + 2.f*(t12 - t10) + (t22 - t20)) * 0.125f;       \
        y[i][8+ch] = ((t20 - t00) + 2.f*(t21 - t01) + (t22 - t02)) * 0.125f;       \
      }                                                                            \
      y[i][3] = scent[C0+i]; y[i][7] = sxs[C0+i]; y[i][11] = sys[C0+i];            \
    }                                                                              \
    float us[CW][4];                                                               \
    _Pragma("unroll")                                                              \
    for (int i = 0; i < CW; ++i) { us[i][0]=b2r0; us[i][1]=b2r1; us[i][2]=b2r2; us[i][3]=b2r3; } \
    for (int o = 0; o < 64; ++o) {  /* wave-uniform scalar weight loads (K$) */    \
      const float* wr = fc1_w + o*12;                                              \
      const float wA=wr[0], wB=wr[1], wC=wr[2], wD=wr[3], wE=wr[4], wF=wr[5],      \
                  wG=wr[6], wH=wr[7], wI=wr[8], wJ=wr[9], wK=wr[10], wL=wr[11];    \
      const float bo = fc1_b[o];                                                   \
      const float q0 = fc2_w[o], q1 = fc2_w[64+o], q2 = fc2_w[128+o], q3 = fc2_w[192+o]; \
      _Pragma("unroll")                                                            \
      for (int i = 0; i < CW; ++i) {                                               \
        float t = bo;                                                              \
        t = fmaf(y[i][0], wA, t); t = fmaf(y[i][1], wB, t);                        \
        t = fmaf(y[i][2], wC, t); t = fmaf(y[i][3], wD, t);                        \
        t = fmaf(y[i][4], wE, t); t = fmaf(y[i][5], wF, t);                        \
        t = fmaf(y[i][6], wG, t); t = fmaf(y[i][7], wH, t);                        \
        t = fmaf(y[i][8], wI, t); t = fmaf(y[i][9], wJ, t);                        \
        t = fmaf(y[i][10], wK, t); t = fmaf(y[i][11], wL, t);                      \
        t = fmaxf(t, 0.f);                                                         \
        us[i][0] = fmaf(t, q0, us[i][0]); us[i][1] = fmaf(t, q1, us[i][1]);        \
        us[i][2] = fmaf(t, q2, us[i][2]); us[i][3] = fmaf(t, q3, us[i][3]);        \
      }                                                                            \
    }                                                                              \
    _Pragma("unroll")                                                              \
    for (int i = 0; i < CW; ++i) {                                                 \
      xs0[C0+i] = y[i][0] + us[i][0]; xs1[C0+i] = y[i][1] + us[i][1];              \
      xs2[C0+i] = y[i][2] + us[i][2]; xs3[C0+i] = y[i][3] + us[i][3];              \
      if (tid + (C0+i)*NT < NPIX) x0buf[pbase[C0+i]] = xs0[C0+i];                  \
    }                                                                              \
  } while (0)

#define SCRN 3616   // x0buf[1296] + hist[1024] + premi[1296]

__global__ __launch_bounds__(NT) __attribute__((amdgpu_waves_per_eu(4, 4)))
void ca_kernel(const float* __restrict__ cell_in,   // [B,4,34,34]
               const float* __restrict__ food_in,   // [B,34,34]
               const float* __restrict__ fc1_w,     // [64,12]
               const float* __restrict__ fc1_b,     // [64]
               const float* __restrict__ fc2_w,     // [4,64]
               const float* __restrict__ fc2_b,     // [4]
               const float* __restrict__ sk_g,      // [19,19]
               const int*   __restrict__ steps_p,
               float* __restrict__ out)             // [cell | food | tpv | lc]
{
  __shared__ float cbuf[3][GP*GP];   // ch0..2; ch3 == scent (step-invariant), never stored
  __shared__ float scratch[SCRN];    // init: 52x52 food; steps: x0buf + hist + premi
  __shared__ int   icl[2][4];        // double-buffered living count
  __shared__ int   inzaz[4];         // packed: nz | az<<16
  __shared__ int   sel_bin, sel_rem;
  __shared__ float fsum[4];
  __shared__ int   lcnt[4];

  float* x0buf = scratch;
  int*   hist  = (int*)(scratch + 1296);
  int*   premi = (int*)(scratch + 2320);   // 1296 ints, halo stays 0

  const int tid  = threadIdx.x;
  const int b    = blockIdx.x;
  const int lane = tid & 63;
  const int wid  = tid >> 6;
  const int nsteps = steps_p[0];

  int pbase[PPT];
#pragma unroll
  for (int i = 0; i < PPT; ++i) {
    int p = tid + i*NT;
    int r = (p < NPIX) ? (p / GD) : 0;
    int c = (p < NPIX) ? (p % GD) : 0;
    pbase[i] = (r+1)*GP + (c+1);
  }

  // ---------------- init ----------------
  for (int idx = tid; idx < 3*GP*GP; idx += NT) (&cbuf[0][0])[idx] = 0.f;
  for (int idx = tid; idx < SCRN;    idx += NT) scratch[idx] = 0.f;
  __syncthreads();

  float v3k[PPT];
  int cnt0 = 0;
#pragma unroll
  for (int i = 0; i < PPT; ++i) {
    v3k[i] = 0.f;
    int p = tid + i*NT;
    if (p < NPIX) {
      int r = p / GD, c = p % GD;
      const float* gi = cell_in + (size_t)b*4*NPIX + p;
      float v0 = gi[0], v1 = gi[NPIX], v2 = gi[2*NPIX], v3 = gi[3*NPIX];
      cbuf[0][pbase[i]] = v0; cbuf[1][pbase[i]] = v1; cbuf[2][pbase[i]] = v2;
      v3k[i] = v3;
      cnt0 += (v0 > 0.8f) ? 1 : 0;
      scratch[(r+9)*52 + (c+9)] = food_in[(size_t)b*NPIX + p];  // 9-halo for 19x19 conv
    }
  }
#pragma unroll
  for (int off = 32; off; off >>= 1) cnt0 += __shfl_down(cnt0, off);
  if (lane == 0) icl[0][wid] = cnt0;
  __syncthreads();

  // scent: 19x19 gaussian conv (once); kernel weights via uniform scalar loads
  float scent[PPT];
#pragma unroll
  for (int i = 0; i < PPT; ++i) {
    float ssum = 0.f;
    int p = tid + i*NT;
    if (p < NPIX) {
      int r = p / GD, c = p % GD;
      for (int dr = 0; dr < 19; ++dr) {
        const float* frow = scratch + (r+dr)*52 + c;
        const float* krow = sk_g + dr*19;
#pragma unroll
        for (int dc = 0; dc < 19; ++dc) ssum = fmaf(frow[dc], krow[dc], ssum);
      }
    }
    scent[i] = ssum;
  }
  __syncthreads();
  for (int idx = tid; idx < SCRN; idx += NT) scratch[idx] = 0.f;
  __syncthreads();
#pragma unroll
  for (int i = 0; i < PPT; ++i) if (tid + i*NT < NPIX) x0buf[pbase[i]] = scent[i];
  __syncthreads();
  // ch3 sobels are step-invariant (ch3 := scent every step): precompute once
  float sxs[PPT], sys[PPT];
#pragma unroll
  for (int i = 0; i < PPT; ++i) {
    const int bb = pbase[i];
    float t00=x0buf[bb-GP-1], t01=x0buf[bb-GP], t02=x0buf[bb-GP+1];
    float t10=x0buf[bb-1],                      t12=x0buf[bb+1];
    float t20=x0buf[bb+GP-1], t21=x0buf[bb+GP], t22=x0buf[bb+GP+1];
    sxs[i] = ((t02 - t00) + 2.f*(t12 - t10) + (t22 - t20)) * 0.125f;
    sys[i] = ((t20 - t00) + 2.f*(t21 - t01) + (t22 - t02)) * 0.125f;
  }
  __syncthreads();
  // x0buf must start zeroed (inactive-wave staleness argument relies on halo=0 only)
#pragma unroll
  for (int i = 0; i < PPT; ++i) if (tid + i*NT < NPIX) x0buf[pbase[i]] = 0.f;

  const float b2r0 = fc2_b[0], b2r1 = fc2_b[1], b2r2 = fc2_b[2], b2r3 = fc2_b[3];

  // ---------------- steps ----------------
  for (int s = 0; s < nsteps; ++s) {
    __syncthreads();                       // syncW: prev writeback -> B1 reads
    // --- B1: premask = maxpool3(ch0) > 0.1 ---
    unsigned pm = 0;
#pragma unroll
    for (int i = 0; i < PPT; ++i) {
      const int bb = pbase[i];
      const float* cb = cbuf[0];
      float m = fmaxf(fmaxf(fmaxf(cb[bb-GP-1],cb[bb-GP]),fmaxf(cb[bb-GP+1],cb[bb-1])),
                fmaxf(fmaxf(cb[bb],cb[bb+1]),fmaxf(fmaxf(cb[bb+GP-1],cb[bb+GP]),cb[bb+GP+1])));
      bool t = (m > 0.1f);
      if (tid + i*NT < NPIX) premi[bb] = t ? 1 : 0;
      if (t) pm |= (1u << i);
    }
    __syncthreads();                       // syncB
    // --- B2: dilated activity; MLP only if this wave has any active pixel ---
    int act = 0;
#pragma unroll
    for (int i = 0; i < PPT; ++i) {
      const int bb = pbase[i];
      int a = premi[bb-GP-1]|premi[bb-GP]|premi[bb-GP+1]|premi[bb-1]|premi[bb]|premi[bb+1]
             |premi[bb+GP-1]|premi[bb+GP]|premi[bb+GP+1];
      if (tid + i*NT < NPIX) act |= a;
    }
    float xs0[PPT], xs1[PPT], xs2[PPT], xs3[PPT];
    if (__any(act)) {
      MLP_CHUNK(0, 2);
      MLP_CHUNK(2, 2);
      MLP_CHUNK(4, 1);
    } else {
      // inactive wave: x0buf stale — only ever consumed by premask-false pixels
#pragma unroll
      for (int i = 0; i < PPT; ++i) { xs0[i]=0.f; xs1[i]=0.f; xs2[i]=0.f; xs3[i]=0.f; }
    }
    __syncthreads();                       // sync2
    // --- C: post_mask, masks+clips, counts (no atomics) ---
    int packed = 0;                        // nz | az<<16
    float v0s[PPT];
#pragma unroll
    for (int i = 0; i < PPT; ++i) {
      v0s[i] = 0.f;
      if (tid + i*NT < NPIX) {
        const int bb = pbase[i];
        float m0 = fmaxf(fmaxf(fmaxf(x0buf[bb-GP-1],x0buf[bb-GP]),fmaxf(x0buf[bb-GP+1],x0buf[bb-1])),
                   fmaxf(fmaxf(x0buf[bb],x0buf[bb+1]),fmaxf(fmaxf(x0buf[bb+GP-1],x0buf[bb+GP]),x0buf[bb+GP+1])));
        bool alive = (m0 > 0.1f) && ((pm >> i) & 1u);
        float v0 = alive ? fminf(fmaxf(xs0[i],   0.f),  1.f) : 0.f;
        float v1 = alive ? fminf(fmaxf(xs1[i], -10.f), 10.f) : 0.f;
        float v2 = alive ? fminf(fmaxf(xs2[i], -10.f), 10.f) : 0.f;
        float v3 = alive ? fminf(fmaxf(xs3[i], -10.f), 10.f) : 0.f;
        cbuf[1][bb] = v1; cbuf[2][bb] = v2; v3k[i] = v3;
        v0s[i] = v0;
        int zer = (v0 == 0.f) ? 1 : 0;
        int azf = (zer && v1 == 0.f && v2 == 0.f && v3 == 0.f) ? 1 : 0;
        packed += zer + (azf << 16);
      }
    }
#pragma unroll
    for (int off = 32; off; off >>= 1) packed += __shfl_down(packed, off);
    if (lane == 0) inzaz[wid] = packed;
    __syncthreads();                       // sync3
    const int t01 = inzaz[0]+inzaz[1]+inzaz[2]+inzaz[3];
    const int nz = t01 & 0xffff, az = t01 >> 16;
    const int cl = icl[s&1][0]+icl[s&1][1]+icl[s&1][2]+icl[s&1][3];
    const int k  = (cl < NPIX) ? cl : (NPIX-1);
    float kth = 0.f;
    if (k >= nz) {                         // rare after first steps: k-th value nonzero -> radix select
      const int k2 = k - nz;
#pragma unroll
      for (int i = 0; i < PPT; ++i) {
        unsigned u = __float_as_uint(v0s[i]);
        if ((tid + i*NT < NPIX) && u != 0u) atomicAdd(&hist[u >> 20], 1);
      }
      __syncthreads();
      SCAN_PASS(k2);
      __syncthreads();
      const int bin1 = sel_bin; const int kr2 = sel_rem;
#pragma unroll
      for (int i = 0; i < PPT; ++i) {
        unsigned u = __float_as_uint(v0s[i]);
        if ((tid + i*NT < NPIX) && u != 0u && (u >> 20) == (unsigned)bin1)
          atomicAdd(&hist[(u >> 10) & 1023u], 1);
      }
      __syncthreads();
      SCAN_PASS(kr2);
      __syncthreads();
      const int bin2 = sel_bin; const int kr3 = sel_rem;
      const unsigned pref2 = (((unsigned)bin1) << 10) | (unsigned)bin2;
#pragma unroll
      for (int i = 0; i < PPT; ++i) {
        unsigned u = __float_as_uint(v0s[i]);
        if ((tid + i*NT < NPIX) && u != 0u && (u >> 10) == pref2)
          atomicAdd(&hist[u & 1023u], 1);
      }
      __syncthreads();
      SCAN_PASS(kr3);
      __syncthreads();
      kth = __uint_as_float((((unsigned)bin1) << 20) | (((unsigned)bin2) << 10) | (unsigned)sel_bin);
    }
    // --- writeback + next step's living count ---
    int cnt = 0;
#pragma unroll
    for (int i = 0; i < PPT; ++i) {
      if (tid + i*NT < NPIX) {
        float w0 = (v0s[i] > kth) ? v0s[i] : 0.f;
        cbuf[0][pbase[i]] = w0;
        cnt += (w0 > 0.8f) ? 1 : 0;
      }
    }
#pragma unroll
    for (int off = 32; off; off >>= 1) cnt += __shfl_down(cnt, off);
    if (lane == 0) icl[(s+1)&1][wid] = cnt;
    if (az == NPIX) break;                 // all-zero state is an exact fixed point
  }

  // ---------------- epilogue ----------------
  const size_t CELL_N = (size_t)4*NPIX*NB;
  const size_t FOOD_N = (size_t)NPIX*NB;
  float tp = 0.f; int lcv = 0;
#pragma unroll
  for (int i = 0; i < PPT; ++i) {
    int p = tid + i*NT;
    if (p < NPIX) {
      const int bb = pbase[i];
      float c0 = cbuf[0][bb], c1 = cbuf[1][bb], c2 = cbuf[2][bb];  // self-written
      size_t go = (size_t)b*4*NPIX + p;
      out[go]          = c0;
      out[go +   NPIX] = c1;
      out[go + 2*NPIX] = c2;
      out[go + 3*NPIX] = v3k[i];
      out[CELL_N + (size_t)b*NPIX + p] = food_in[(size_t)b*NPIX + p];
      tp += c0;
      lcv += (c0 > 0.1f) ? 1 : 0;
    }
  }
#pragma unroll
  for (int off = 32; off; off >>= 1) { tp += __shfl_down(tp, off); lcv += __shfl_down(lcv, off); }
  if (lane == 0) { fsum[wid] = tp; lcnt[wid] = lcv; }
  __syncthreads();
  if (tid == 0) {
    out[CELL_N + FOOD_N + b]      = fsum[0]+fsum[1]+fsum[2]+fsum[3];
    out[CELL_N + FOOD_N + NB + b] = (float)(lcnt[0]+lcnt[1]+lcnt[2]+lcnt[3]);
  }
}

extern "C" void kernel_launch(void* const* d_in, const int* in_sizes, int n_in,
                              void* d_out, int out_size, void* d_ws, size_t ws_size,
                              hipStream_t stream) {
  const float* cell  = (const float*)d_in[0];
  const float* food  = (const float*)d_in[1];
  const float* fc1w  = (const float*)d_in[2];
  const float* fc1b  = (const float*)d_in[3];
  const float* fc2w  = (const float*)d_in[4];
  const float* fc2b  = (const float*)d_in[5];
  const float* sk    = (const float*)d_in[6];
  const int*   steps = (const int*)d_in[7];
  float* out = (float*)d_out;
  ca_kernel<<<NB, NT, 0, stream>>>(cell, food, fc1w, fc1b, fc2w, fc2b, sk, steps, out);
}

// Round 4
// 265.280 us; speedup vs baseline: 6.0919x; 1.4338x over previous
//
#include <hip/hip_runtime.h>
#include <stdint.h>

#define GD    34
#define GP    36          // padded grid (zero halo)
#define NPIX  1156
#define NT    256
#define NB    1024
#define TPR   7           // 5-pixel strips per row (7*5=35 >= 34)
#define TUSED 238         // 34 rows * 7 strips

// wave0 scans the 1024-bin LDS histogram, finds the bin containing rank KK,
// writes sel_bin/sel_rem, zeroes the histogram behind itself.
#define SCAN_PASS(KK) do {                                                         \
    if (wid == 0) {                                                                \
      const int base2 = lane << 4;                                                 \
      int c16[16]; int csum = 0;                                                   \
      _Pragma("unroll")                                                            \
      for (int j = 0; j < 16; ++j) { c16[j] = hist[base2+j]; hist[base2+j] = 0; csum += c16[j]; } \
      int inc = csum;                                                              \
      _Pragma("unroll")                                                            \
      for (int off2 = 1; off2 < 64; off2 <<= 1) { int vv = __shfl_up(inc, off2); if (lane >= off2) inc += vv; } \
      const int excl = inc - csum;                                                 \
      if ((KK) >= excl && (KK) < inc) {                                            \
        int rem = (KK) - excl; int cum = 0;                                        \
        _Pragma("unroll")                                                          \
        for (int j = 0; j < 16; ++j) {                                             \
          if (rem >= cum && rem < cum + c16[j]) { sel_bin = base2 + j; sel_rem = rem - cum; } \
          cum += c16[j];                                                           \
        }                                                                          \
      }                                                                            \
    }                                                                              \
  } while (0)

#define SCRN 4904   // x0buf[1296] | x1s[1156] | x2s[1156] | premi[1296]; hist aliases x1s

__global__ __launch_bounds__(NT) __attribute__((amdgpu_waves_per_eu(4, 4)))
void ca_kernel(const float* __restrict__ cell_in,   // [B,4,34,34]
               const float* __restrict__ food_in,   // [B,34,34]
               const float* __restrict__ fc1_w,     // [64,12] (wave-uniform scalar reads)
               const float* __restrict__ fc1_b,     // [64]
               const float* __restrict__ fc2_w,     // [4,64]
               const float* __restrict__ fc2_b,     // [4]
               const float* __restrict__ sk_g,      // [19,19]
               const int*   __restrict__ steps_p,
               float* __restrict__ out)             // [cell | food | tpv | lc]
{
  __shared__ float cbuf[3][GP*GP];   // ch0..2; ch3 == scent (step-invariant), never stored
  __shared__ float scratch[SCRN];
  __shared__ int   icl[2][4];
  __shared__ int   inzaz[4];
  __shared__ int   sel_bin, sel_rem;
  __shared__ float fsum[4];
  __shared__ int   lcnt[4];

  float* x0buf = scratch;                       // 36x36 halo'd, x_new ch0 (pre-mask/clip)
  float* x1s   = scratch + 1296;                // flat [1156] staging of x_new ch1
  float* x2s   = scratch + 2452;                // flat [1156] staging of x_new ch2
  int*   premi = (int*)(scratch + 3608);        // 36x36 halo'd premask ints (halo stays 0)
  int*   hist  = (int*)(scratch + 1296);        // aliases x1s: only live inside radix path

  const int tid  = threadIdx.x;
  const int b    = blockIdx.x;
  const int lane = tid & 63;
  const int wid  = tid >> 6;
  const int nsteps = steps_p[0];

  const bool tval = (tid < TUSED);
  const int  trow = tval ? (tid / TPR) : 0;
  const int  c0   = tval ? ((tid % TPR) * 5) : 0;
  const int  nval = tval ? ((c0 <= 29) ? 5 : 4) : 0;   // strip 6 covers cols 30..33
  const int  pb0  = tval ? ((trow+1)*GP + c0 + 1) : 37; // padded base (safe interior if idle)
  const int  p0   = trow*GD + c0;                       // flat pixel base

  // ---------------- init ----------------
  for (int idx = tid; idx < 3*GP*GP; idx += NT) (&cbuf[0][0])[idx] = 0.f;
  for (int idx = tid; idx < SCRN;    idx += NT) scratch[idx] = 0.f;
  __syncthreads();

  float v3k[5];
  int cnt0 = 0;
#pragma unroll
  for (int j = 0; j < 5; ++j) {
    v3k[j] = 0.f;
    if (j < nval) {
      int p = p0 + j;
      const float* gi = cell_in + (size_t)b*4*NPIX + p;
      float v0 = gi[0], v1 = gi[NPIX], v2 = gi[2*NPIX], v3 = gi[3*NPIX];
      cbuf[0][pb0+j] = v0; cbuf[1][pb0+j] = v1; cbuf[2][pb0+j] = v2;
      v3k[j] = v3;
      cnt0 += (v0 > 0.8f) ? 1 : 0;
      scratch[(trow+9)*52 + (c0+j+9)] = food_in[(size_t)b*NPIX + p];  // 9-halo 52x52
    }
  }
#pragma unroll
  for (int off = 32; off; off >>= 1) cnt0 += __shfl_down(cnt0, off);
  if (lane == 0) icl[0][wid] = cnt0;
  __syncthreads();

  // scent: 19x19 gaussian conv, once
  float scent[5];
#pragma unroll
  for (int j = 0; j < 5; ++j) {
    float ssum = 0.f;
    if (j < nval) {
      for (int dr = 0; dr < 19; ++dr) {
        const float* frow = scratch + (trow+dr)*52 + (c0+j);
        const float* krow = sk_g + dr*19;
#pragma unroll
        for (int dc = 0; dc < 19; ++dc) ssum = fmaf(frow[dc], krow[dc], ssum);
      }
    }
    scent[j] = ssum;
  }
  __syncthreads();
  for (int idx = tid; idx < SCRN; idx += NT) scratch[idx] = 0.f;  // premi halo must be 0
  __syncthreads();
#pragma unroll
  for (int j = 0; j < 5; ++j) if (j < nval) x0buf[pb0+j] = scent[j];
  __syncthreads();
  // ch3 := scent every step -> its sobels are step-invariant
  float sxs[5], sys[5];
#pragma unroll
  for (int j = 0; j < 5; ++j) {
    const int bb = (j < nval) ? (pb0 + j) : pb0;
    float t00=x0buf[bb-GP-1], t01=x0buf[bb-GP], t02=x0buf[bb-GP+1];
    float t10=x0buf[bb-1],                      t12=x0buf[bb+1];
    float t20=x0buf[bb+GP-1], t21=x0buf[bb+GP], t22=x0buf[bb+GP+1];
    sxs[j] = ((t02 - t00) + 2.f*(t12 - t10) + (t22 - t20)) * 0.125f;
    sys[j] = ((t20 - t00) + 2.f*(t21 - t01) + (t22 - t02)) * 0.125f;
  }
  // x0buf content is stale-safe (only premask-false pixels ever read stale entries)

  const float b2r0 = fc2_b[0], b2r1 = fc2_b[1], b2r2 = fc2_b[2], b2r3 = fc2_b[3];

  // ---------------- steps ----------------
  for (int s = 0; s < nsteps; ++s) {
    __syncthreads();                       // syncW: prev writeback -> B1 reads
    // --- B1: premask = maxpool3(ch0) > 0.1, rolling 7-col window ---
    float cm[7];
#pragma unroll
    for (int jc = 0; jc < 7; ++jc) {
      cm[jc] = 0.f;
      if (jc < nval + 2) {
        const int a = pb0 - 1 + jc;
        cm[jc] = fmaxf(fmaxf(cbuf[0][a-GP], cbuf[0][a]), cbuf[0][a+GP]);
      }
    }
    unsigned pm = 0;
#pragma unroll
    for (int j = 0; j < 5; ++j) {
      if (j < nval) {
        bool t = fmaxf(fmaxf(cm[j], cm[j+1]), cm[j+2]) > 0.1f;
        premi[pb0+j] = t ? 1 : 0;
        if (t) pm |= (1u << j);
      }
    }
    __syncthreads();                       // syncB
    // --- B2: per-pixel dilated activity (rolling OR) + gated per-pixel MLP ---
    int co[7];
#pragma unroll
    for (int jc = 0; jc < 7; ++jc) {
      co[jc] = 0;
      if (jc < nval + 2) {
        const int a = pb0 - 1 + jc;
        co[jc] = premi[a-GP] | premi[a] | premi[a+GP];
      }
    }
#pragma unroll
    for (int j = 0; j < 5; ++j) {
      int acti = (j < nval) ? (co[j] | co[j+1] | co[j+2]) : 0;
      if (__any(acti)) {
        const int bb = (j < nval) ? (pb0 + j) : pb0;
        float y0,y1,y2,y4,y5,y6,y8,y9,y10;
        {
          const float* cb = cbuf[0];
          float t00=cb[bb-GP-1], t01=cb[bb-GP], t02=cb[bb-GP+1];
          float t10=cb[bb-1],    t11=cb[bb],    t12=cb[bb+1];
          float t20=cb[bb+GP-1], t21=cb[bb+GP], t22=cb[bb+GP+1];
          y0 = t11;
          y4 = ((t02 - t00) + 2.f*(t12 - t10) + (t22 - t20)) * 0.125f;
          y8 = ((t20 - t00) + 2.f*(t21 - t01) + (t22 - t02)) * 0.125f;
        }
        {
          const float* cb = cbuf[1];
          float t00=cb[bb-GP-1], t01=cb[bb-GP], t02=cb[bb-GP+1];
          float t10=cb[bb-1],    t11=cb[bb],    t12=cb[bb+1];
          float t20=cb[bb+GP-1], t21=cb[bb+GP], t22=cb[bb+GP+1];
          y1 = t11;
          y5 = ((t02 - t00) + 2.f*(t12 - t10) + (t22 - t20)) * 0.125f;
          y9 = ((t20 - t00) + 2.f*(t21 - t01) + (t22 - t02)) * 0.125f;
        }
        {
          const float* cb = cbuf[2];
          float t00=cb[bb-GP-1], t01=cb[bb-GP], t02=cb[bb-GP+1];
          float t10=cb[bb-1],    t11=cb[bb],    t12=cb[bb+1];
          float t20=cb[bb+GP-1], t21=cb[bb+GP], t22=cb[bb+GP+1];
          y2 = t11;
          y6 = ((t02 - t00) + 2.f*(t12 - t10) + (t22 - t20)) * 0.125f;
          y10= ((t20 - t00) + 2.f*(t21 - t01) + (t22 - t02)) * 0.125f;
        }
        const float y3 = scent[j], y7 = sxs[j], y11 = sys[j];
        float u0 = b2r0, u1 = b2r1, u2 = b2r2, u3 = b2r3;
        for (int o = 0; o < 64; ++o) {     // weights: wave-uniform scalar loads (K$)
          const float* wr = fc1_w + o*12;
          float t = fc1_b[o];
          t = fmaf(y0, wr[0], t);  t = fmaf(y1, wr[1], t);
          t = fmaf(y2, wr[2], t);  t = fmaf(y3, wr[3], t);
          t = fmaf(y4, wr[4], t);  t = fmaf(y5, wr[5], t);
          t = fmaf(y6, wr[6], t);  t = fmaf(y7, wr[7], t);
          t = fmaf(y8, wr[8], t);  t = fmaf(y9, wr[9], t);
          t = fmaf(y10, wr[10], t); t = fmaf(y11, wr[11], t);
          t = fmaxf(t, 0.f);
          u0 = fmaf(t, fc2_w[o],     u0);
          u1 = fmaf(t, fc2_w[64+o],  u1);
          u2 = fmaf(t, fc2_w[128+o], u2);
          u3 = fmaf(t, fc2_w[192+o], u3);
        }
        v3k[j] = y3 + u3;                  // x_new ch3, pre-clip, held in-place
        if (j < nval) {
          x0buf[bb]    = y0 + u0;          // x_new ch0, pre-mask/clip (for postmask pool)
          x1s[p0 + j]  = y1 + u1;
          x2s[p0 + j]  = y2 + u2;
        }
      }
    }
    __syncthreads();                       // sync2
    // --- C: postmask (only where premask), masks+clips, counts ---
    unsigned pq = 0;
    float midv[5];
#pragma unroll
    for (int j = 0; j < 5; ++j) midv[j] = 0.f;
    if (pm) {
      float dm[7];
#pragma unroll
      for (int jc = 0; jc < 7; ++jc) {
        dm[jc] = 0.f;
        if (jc < nval + 2) {
          const int a = pb0 - 1 + jc;
          float u = x0buf[a-GP], m = x0buf[a], d = x0buf[a+GP];
          dm[jc] = fmaxf(fmaxf(u, m), d);
          if (jc >= 1 && jc <= 5) midv[jc-1] = m;   // own x_new ch0 values
        }
      }
#pragma unroll
      for (int j = 0; j < 5; ++j)
        if (fmaxf(fmaxf(dm[j], dm[j+1]), dm[j+2]) > 0.1f) pq |= (1u << j);
    }
    int packed = 0;                        // nz | az<<16
    float v0s[5];
#pragma unroll
    for (int j = 0; j < 5; ++j) {
      v0s[j] = 0.f;
      if (j < nval) {
        bool alive = ((pm >> j) & 1u) && ((pq >> j) & 1u);
        float v0 = 0.f, v1 = 0.f, v2 = 0.f, v3 = 0.f;
        if (alive) {
          v0 = fminf(fmaxf(midv[j],      0.f),  1.f);
          v1 = fminf(fmaxf(x1s[p0+j], -10.f), 10.f);
          v2 = fminf(fmaxf(x2s[p0+j], -10.f), 10.f);
          v3 = fminf(fmaxf(v3k[j],    -10.f), 10.f);
        }
        cbuf[1][pb0+j] = v1; cbuf[2][pb0+j] = v2; v3k[j] = v3;
        v0s[j] = v0;
        int zer = (v0 == 0.f) ? 1 : 0;
        int azf = (zer && v1 == 0.f && v2 == 0.f && v3 == 0.f) ? 1 : 0;
        packed += zer + (azf << 16);
      }
    }
#pragma unroll
    for (int off = 32; off; off >>= 1) packed += __shfl_down(packed, off);
    if (lane == 0) inzaz[wid] = packed;
    __syncthreads();                       // sync3 (x1s/x2s fully consumed after this)
    const int t01 = inzaz[0]+inzaz[1]+inzaz[2]+inzaz[3];
    const int nz = t01 & 0xffff, az = t01 >> 16;
    const int cl = icl[s&1][0]+icl[s&1][1]+icl[s&1][2]+icl[s&1][3];
    const int k  = (cl < NPIX) ? cl : (NPIX-1);
    float kth = 0.f;
    if (k >= nz) {                         // rare: k-th value nonzero -> 3-pass radix select
      hist[tid] = 0; hist[tid+256] = 0; hist[tid+512] = 0; hist[tid+768] = 0;  // hist aliases x1s
      __syncthreads();
      const int k2 = k - nz;
#pragma unroll
      for (int j = 0; j < 5; ++j) {
        unsigned u = __float_as_uint(v0s[j]);
        if (j < nval && u != 0u) atomicAdd(&hist[u >> 20], 1);
      }
      __syncthreads();
      SCAN_PASS(k2);
      __syncthreads();
      const int bin1 = sel_bin; const int kr2 = sel_rem;
#pragma unroll
      for (int j = 0; j < 5; ++j) {
        unsigned u = __float_as_uint(v0s[j]);
        if (j < nval && u != 0u && (u >> 20) == (unsigned)bin1)
          atomicAdd(&hist[(u >> 10) & 1023u], 1);
      }
      __syncthreads();
      SCAN_PASS(kr2);
      __syncthreads();
      const int bin2 = sel_bin; const int kr3 = sel_rem;
      const unsigned pref2 = (((unsigned)bin1) << 10) | (unsigned)bin2;
#pragma unroll
      for (int j = 0; j < 5; ++j) {
        unsigned u = __float_as_uint(v0s[j]);
        if (j < nval && u != 0u && (u >> 10) == pref2)
          atomicAdd(&hist[u & 1023u], 1);
      }
      __syncthreads();
      SCAN_PASS(kr3);
      __syncthreads();
      kth = __uint_as_float((((unsigned)bin1) << 20) | (((unsigned)bin2) << 10) | (unsigned)sel_bin);
      // SCAN_PASS self-clears hist -> x1s region left zeroed; premi region untouched
    }
    // --- writeback + next step's living count ---
    int cnt = 0;
#pragma unroll
    for (int j = 0; j < 5; ++j) {
      if (j < nval) {
        float w0 = (v0s[j] > kth) ? v0s[j] : 0.f;
        cbuf[0][pb0+j] = w0;
        cnt += (w0 > 0.8f) ? 1 : 0;
      }
    }
#pragma unroll
    for (int off = 32; off; off >>= 1) cnt += __shfl_down(cnt, off);
    if (lane == 0) icl[(s+1)&1][wid] = cnt;
    if (az == NPIX) break;                 // all-zero state is an exact fixed point
  }

  // ---------------- epilogue ----------------
  const size_t CELL_N = (size_t)4*NPIX*NB;
  const size_t FOOD_N = (size_t)NPIX*NB;
  float tp = 0.f; int lcv = 0;
#pragma unroll
  for (int j = 0; j < 5; ++j) {
    if (j < nval) {
      const int p = p0 + j;
      float c0v = cbuf[0][pb0+j], c1 = cbuf[1][pb0+j], c2 = cbuf[2][pb0+j]; // self-written
      size_t go = (size_t)b*4*NPIX + p;
      out[go]          = c0v;
      out[go +   NPIX] = c1;
      out[go + 2*NPIX] = c2;
      out[go + 3*NPIX] = v3k[j];
      out[CELL_N + (size_t)b*NPIX + p] = food_in[(size_t)b*NPIX + p];
      tp += c0v;
      lcv += (c0v > 0.1f) ? 1 : 0;
    }
  }
#pragma unroll
  for (int off = 32; off; off >>= 1) { tp += __shfl_down(tp, off); lcv += __shfl_down(lcv, off); }
  if (lane == 0) { fsum[wid] = tp; lcnt[wid] = lcv; }
  __syncthreads();
  if (tid == 0) {
    out[CELL_N + FOOD_N + b]      = fsum[0]+fsum[1]+fsum[2]+fsum[3];
    out[CELL_N + FOOD_N + NB + b] = (float)(lcnt[0]+lcnt[1]+lcnt[2]+lcnt[3]);
  }
}

extern "C" void kernel_launch(void* const* d_in, const int* in_sizes, int n_in,
                              void* d_out, int out_size, void* d_ws, size_t ws_size,
                              hipStream_t stream) {
  const float* cell  = (const float*)d_in[0];
  const float* food  = (const float*)d_in[1];
  const float* fc1w  = (const float*)d_in[2];
  const float* fc1b  = (const float*)d_in[3];
  const float* fc2w  = (const float*)d_in[4];
  const float* fc2b  = (const float*)d_in[5];
  const float* sk    = (const float*)d_in[6];
  const int*   steps = (const int*)d_in[7];
  float* out = (float*)d_out;
  ca_kernel<<<NB, NT, 0, stream>>>(cell, food, fc1w, fc1b, fc2w, fc2b, sk, steps, out);
}